// Round 17
// baseline (196.697 us; speedup 1.0000x reference)
//
#include <hip/hip_runtime.h>

// SNN layer on MI355X. i[t,b,o] = sum_k x[b,k,t]*w[k,o]; per-(b,o) sequential
// LIF scan over t; spikes (0/1) fp32 [B,O,T].
//
// Exact fixed-point i8-MFMA path (rounds 7-16 proven, absmax 0.0):
// X=rint(x*2^28) -> 4 signed i8 limbs, W=rint(w*2^15) -> 4 limbs; 13 limb
// pairs (p+q>=2) accumulated exactly in i32 (mfma_i32_16x16x64_i8), combined
// in fp64; eps_i ~ 3e-4 vs ~2e-3 budget. Integer accumulation exact ->
// instruction order cannot change results.
//
// r16 post-mortem: SLOT reorder (13 limb-pair slots x 4 independent MFMAs)
// dropped VGPR 128->68 and FETCH 434->42MB; kernel now MFMA-issue-bound at
// 2 waves/SIMD (MfmaUtil 31% == 46us busy ~= 56us serialization floor).
// This round: r13's 8-wave fused structure (512 thr, block tile 128t x 64o,
// SAME 32t x 32o wave tile, two-phase ib reuse) -- r13 failed only on a
// VGPR spill (needed 144 vs cap 128); at 68 VGPR it fits. 2 blocks/CU x
// 8 waves = 4 waves/SIMD: 2x MFMA issue density, no iw round-trip.

#define NB 64
#define NI 512
#define NO 512
#define NT 500

typedef int v4i __attribute__((ext_vector_type(4)));
typedef double d2 __attribute__((ext_vector_type(2)));

#define XT_B_STRIDE 1048576   // bytes per batch in XT
#define P_STRIDE    262144    // bytes per limb plane
#define KB_STRIDE   8192      // bytes per k-block (512 rows * 16B)
#define XT_BYTES    67108864
#define WT_BYTES    1048576
#define WS_NEED     ((size_t)XT_BYTES + WT_BYTES)   // 68,157,440

// ============ prep: x transpose+limb-slice (blocks 0..511), w (512..519) ====
__global__ __launch_bounds__(256)
void prep_xw(const float* __restrict__ xg, const float* __restrict__ wg,
             unsigned char* __restrict__ xt, unsigned char* __restrict__ wtb) {
    __shared__ float xs[64][65];
    const int tid = threadIdx.x;
    const int sk  = tid >> 2;
    const int st  = (tid & 3) * 16;
    const int ct  = tid & 63;
    const int ckb = tid >> 6;

    if (blockIdx.x < 512) {
        const int b  = blockIdx.x >> 3;
        const int kc = (blockIdx.x & 7) * 64;
        for (int tc = 0; tc < 512; tc += 64) {
            __syncthreads();
            const float* px = xg + ((size_t)(b * NI + kc + sk)) * NT + tc + st;
            #pragma unroll
            for (int e = 0; e < 16; ++e)
                xs[sk][st + e] = (tc + st + e < NT) ? px[e] : 0.0f;
            __syncthreads();

            unsigned int u0[4] = {0,0,0,0}, u1[4] = {0,0,0,0};
            unsigned int u2[4] = {0,0,0,0}, u3[4] = {0,0,0,0};
            #pragma unroll
            for (int e = 0; e < 16; ++e) {
                const float xv = xs[ckb * 16 + e][ct];
                int X = __float2int_rn(xv * 268435456.0f);    // x * 2^28
                const int a0 = (X << 24) >> 24; X = (X - a0) >> 8;
                const int a1 = (X << 24) >> 24; X = (X - a1) >> 8;
                const int a2 = (X << 24) >> 24; const int a3 = (X - a2) >> 8;
                const int sh = (e & 3) * 8; const int d = e >> 2;
                u0[d] |= (unsigned)(a0 & 0xFF) << sh;
                u1[d] |= (unsigned)(a1 & 0xFF) << sh;
                u2[d] |= (unsigned)(a2 & 0xFF) << sh;
                u3[d] |= (unsigned)(a3 & 0xFF) << sh;
            }
            unsigned char* base = xt + (size_t)b * XT_B_STRIDE
                                  + (size_t)(kc / 16 + ckb) * KB_STRIDE
                                  + (size_t)(tc + ct) * 16;
            *(uint4*)(base)                = make_uint4(u0[0], u0[1], u0[2], u0[3]);
            *(uint4*)(base + P_STRIDE)     = make_uint4(u1[0], u1[1], u1[2], u1[3]);
            *(uint4*)(base + 2 * P_STRIDE) = make_uint4(u2[0], u2[1], u2[2], u2[3]);
            *(uint4*)(base + 3 * P_STRIDE) = make_uint4(u3[0], u3[1], u3[2], u3[3]);
        }
    } else {
        const int kc = (blockIdx.x - 512) * 64;
        for (int oc = 0; oc < 512; oc += 64) {
            __syncthreads();
            const float* pw = wg + (size_t)(kc + sk) * NO + oc + st;
            #pragma unroll
            for (int e = 0; e < 16; e += 4) {
                float4 f = *(const float4*)(pw + e);
                xs[sk][st + e + 0] = f.x; xs[sk][st + e + 1] = f.y;
                xs[sk][st + e + 2] = f.z; xs[sk][st + e + 3] = f.w;
            }
            __syncthreads();

            unsigned int u0[4] = {0,0,0,0}, u1[4] = {0,0,0,0};
            unsigned int u2[4] = {0,0,0,0}, u3[4] = {0,0,0,0};
            #pragma unroll
            for (int e = 0; e < 16; ++e) {
                const float wv = xs[ckb * 16 + e][ct];
                int X = __float2int_rn(wv * 32768.0f);        // w * 2^15
                const int a0 = (X << 24) >> 24; X = (X - a0) >> 8;
                const int a1 = (X << 24) >> 24; X = (X - a1) >> 8;
                const int a2 = (X << 24) >> 24; const int a3 = (X - a2) >> 8;
                const int sh = (e & 3) * 8; const int d = e >> 2;
                u0[d] |= (unsigned)(a0 & 0xFF) << sh;
                u1[d] |= (unsigned)(a1 & 0xFF) << sh;
                u2[d] |= (unsigned)(a2 & 0xFF) << sh;
                u3[d] |= (unsigned)(a3 & 0xFF) << sh;
            }
            unsigned char* base = wtb + (size_t)(kc / 16 + ckb) * KB_STRIDE
                                  + (size_t)(oc + ct) * 16;
            *(uint4*)(base)                = make_uint4(u0[0], u0[1], u0[2], u0[3]);
            *(uint4*)(base + P_STRIDE)     = make_uint4(u1[0], u1[1], u1[2], u1[3]);
            *(uint4*)(base + 2 * P_STRIDE) = make_uint4(u2[0], u2[1], u2[2], u2[3]);
            *(uint4*)(base + 3 * P_STRIDE) = make_uint4(u3[0], u3[1], u3[2], u3[3]);
        }
    }
}

// ====== main: 8-wave register-direct i8-MFMA GEMM + fused two-phase scan ======
#define MFMA_I8(a, b, c) __builtin_amdgcn_mfma_i32_16x16x64_i8(a, b, c, 0, 0, 0)

// one limb-pair slot: 4 independent MFMAs (ta,oc); no same-acc adjacency
#define SLOT(ACC, AI, BI)                                              \
    _Pragma("unroll")                                                  \
    for (int ta = 0; ta < 2; ++ta) {                                   \
        _Pragma("unroll")                                              \
        for (int oc = 0; oc < 2; ++oc)                                 \
            ACC[ta][oc] = MFMA_I8(aF[ta][AI], bF[oc][BI], ACC[ta][oc]);\
    }

__global__ __launch_bounds__(512, 2)
void snn_i8x8(const unsigned char* __restrict__ xt,
              const unsigned char* __restrict__ wtb,
              float* __restrict__ yg) {
    __shared__ double ib[64][66];        // 33,792 B (reused for both t-halves)

    const int tid  = threadIdx.x;
    const int lane = tid & 63;
    const int wv   = tid >> 6;      // wave 0..7
    const int wt   = wv & 3;        // t-quarter of 128-t chunk (32 rows each)
    const int wo   = wv >> 2;       // o-half (32 cols)
    const int lr   = lane & 15;
    const int lg   = lane >> 4;

    // XCD swizzle (proven): 8 o-tiles of one batch share an XCD.
    const int L  = blockIdx.x;
    const int b  = (L & 7) + ((L >> 6) << 3);
    const int o0 = ((L >> 3) & 7) * 64;

    const unsigned char* xb = xt + (size_t)b * XT_B_STRIDE;
    const unsigned char* wb = wtb + (size_t)o0 * 16;

    const double alpha = 0.001 / 50.0;
    double v = 0.0;                 // scan state (lanes<8 of each wave)

    for (int tc = 0; tc < 4; ++tc) {            // 4 chunks of 128 t (512 padded)
        v4i acc0[2][2], acc1[2][2], acc2[2][2], acc3[2][2], acc4[2][2];
        #pragma unroll
        for (int ta = 0; ta < 2; ++ta)
            #pragma unroll
            for (int oc = 0; oc < 2; ++oc) {
                acc0[ta][oc] = (v4i){0,0,0,0}; acc1[ta][oc] = (v4i){0,0,0,0};
                acc2[ta][oc] = (v4i){0,0,0,0}; acc3[ta][oc] = (v4i){0,0,0,0};
                acc4[ta][oc] = (v4i){0,0,0,0};
            }

        const int tbase = tc * 128 + wt * 32;    // wave's 32-t strip in XT

        for (int kw = 0; kw < 8; ++kw) {         // plain loads; TLP hides latency
            const size_t kb0 = (size_t)(kw * 4 + lg) * KB_STRIDE;
            v4i aF[2][4], bF[2][4];
            #pragma unroll
            for (int p = 0; p < 4; ++p) {
                const size_t pp = (size_t)p * P_STRIDE + kb0;
                #pragma unroll
                for (int ta = 0; ta < 2; ++ta)
                    aF[ta][p] = *(const v4i*)(xb + pp
                                 + (size_t)(tbase + ta * 16 + lr) * 16);
                #pragma unroll
                for (int oc = 0; oc < 2; ++oc)
                    bF[oc][p] = *(const v4i*)(wb + pp
                                 + (size_t)(wo * 32 + oc * 16 + lr) * 16);
            }
            // 13 limb-pair slots, interleaved across accumulators (r16-proven):
            SLOT(acc0, 0, 2)  SLOT(acc1, 0, 3)  SLOT(acc2, 1, 3)
            SLOT(acc3, 2, 3)  SLOT(acc4, 3, 3)
            SLOT(acc0, 1, 1)  SLOT(acc1, 1, 2)  SLOT(acc2, 2, 2)
            SLOT(acc3, 3, 2)
            SLOT(acc0, 2, 0)  SLOT(acc1, 2, 1)  SLOT(acc2, 3, 1)
            SLOT(acc1, 3, 0)
        }

        // ---- two 64-t phases: write ib + scan (ib reused) ----
        #pragma unroll
        for (int ph = 0; ph < 2; ++ph) {
            __syncthreads();   // prior phase's scan reads (or prior chunk) done
            if ((wt >> 1) == ph) {
                // D: col = lane&15 (o), row = 4*(lane>>4)+reg -- HW-verified.
                const int trow = (wt & 1) * 32;
                #pragma unroll
                for (int ta = 0; ta < 2; ++ta)
                    #pragma unroll
                    for (int oc = 0; oc < 2; ++oc) {
                        const int o_loc = wo * 32 + oc * 16 + lr;
                        #pragma unroll
                        for (int r = 0; r < 4; ++r) {
                            const double iv =
                                  (double)acc0[ta][oc][r] * 0x1p-27
                                + (double)acc1[ta][oc][r] * 0x1p-19
                                + (double)acc2[ta][oc][r] * 0x1p-11
                                + (double)acc3[ta][oc][r] * 0x1p-3
                                + (double)acc4[ta][oc][r] * 0x1p+5;
                            ib[trow + ta * 16 + lg * 4 + r][o_loc] = iv;
                        }
                    }
            }
            __syncthreads();

            // scan: 8 waves x 8 o-channels (lanes 0..7), 64 t this phase
            if (lane < 8) {
                const int ol  = wv * 8 + lane;           // local o 0..63
                const int t0g = tc * 128 + ph * 64;
                float* py = yg + ((size_t)(b * NO) + o0 + ol) * NT + t0g;
                #pragma unroll
                for (int tb = 0; tb < 4; ++tb) {
                    double iv[16];
                    #pragma unroll
                    for (int u = 0; u < 16; ++u) iv[u] = ib[tb * 16 + u][ol];
                    float fv[16];
                    #pragma unroll
                    for (int u = 0; u < 16; ++u) {
                        v += (iv[u] - v) * alpha;
                        const bool s = (v >= 1.0);
                        fv[u] = s ? 1.0f : 0.0f;
                        if (s) v = 0.0;
                    }
                    const int tg = t0g + tb * 16;
                    #pragma unroll
                    for (int q = 0; q < 4; ++q)
                        if (tg + q * 4 < NT)
                            *(float4*)(py + tb * 16 + q * 4) =
                                make_float4(fv[q*4], fv[q*4+1], fv[q*4+2], fv[q*4+3]);
                }
            }
        }
    }
}

// ============ fallback: round-4 fused fp64 kernel (ws-free, proven) ============
#define OT 64
#define TT 64
#define KC 32
#define TP (TT + 2)
#define OP (OT + 2)

__global__ __launch_bounds__(256, 2)
void snn_v2(const float* __restrict__ xg, const float* __restrict__ wg,
            float* __restrict__ yg) {
    __shared__ double smem[KC * TP + KC * OP];
    double (*xs)[TP]  = (double(*)[TP])smem;
    double (*wsh)[OP] = (double(*)[OP])(smem + KC * TP);
    double (*ib)[OP]  = (double(*)[OP])smem;

    const int tid = threadIdx.x;
    const int p2  = (tid & 31) * 2;
    const int t0  = (tid >> 5) * 8;
    const int L   = blockIdx.x;
    const int b   = (L & 7) + ((L >> 6) << 3);
    const int o0  = ((L >> 3) & 7) * OT;
    const int sk  = tid >> 3;
    const int se  = (tid & 7) * 8;
    const double alpha = 0.001 / 50.0;
    double v = 0.0;

    for (int tc = 0; tc < NT; tc += TT) {
        const int tlim = (NT - tc < TT) ? (NT - tc) : TT;
        double a0[8], a1[8];
        #pragma unroll
        for (int j = 0; j < 8; ++j) { a0[j] = 0.0; a1[j] = 0.0; }

        for (int kc = 0; kc < NI; kc += KC) {
            __syncthreads();
            {
                const float* px = xg + ((size_t)(b * NI + kc + sk)) * NT + tc + se;
                double* dx = &xs[sk][se];
                if (tlim == TT) {
                    #pragma unroll
                    for (int e = 0; e < 2; ++e) {
                        float4 f = ((const float4*)px)[e];
                        d2 lo = {(double)f.x, (double)f.y};
                        d2 hi = {(double)f.z, (double)f.w};
                        *(d2*)(dx + e * 4) = lo; *(d2*)(dx + e * 4 + 2) = hi;
                    }
                } else {
                    #pragma unroll
                    for (int e = 0; e < 8; ++e) {
                        double val = 0.0;
                        if (se + e < tlim) val = (double)px[e];
                        dx[e] = val;
                    }
                }
            }
            {
                const float* pw = wg + (size_t)(kc + sk) * NO + o0 + se;
                double* dw = &wsh[sk][se];
                #pragma unroll
                for (int e = 0; e < 2; ++e) {
                    float4 f = ((const float4*)pw)[e];
                    d2 lo = {(double)f.x, (double)f.y};
                    d2 hi = {(double)f.z, (double)f.w};
                    *(d2*)(dw + e * 4) = lo; *(d2*)(dw + e * 4 + 2) = hi;
                }
            }
            __syncthreads();
            #pragma unroll 4
            for (int k = 0; k < KC; ++k) {
                const d2 w2 = *(const d2*)&wsh[k][p2];
                double x8[8];
                #pragma unroll
                for (int e = 0; e < 4; ++e)
                    *(d2*)&x8[e * 2] = *(const d2*)&xs[k][t0 + e * 2];
                #pragma unroll
                for (int j = 0; j < 8; ++j) {
                    a0[j] += x8[j] * w2[0];
                    a1[j] += x8[j] * w2[1];
                }
            }
        }
        __syncthreads();
        #pragma unroll
        for (int j = 0; j < 8; ++j) {
            d2 c = {a0[j], a1[j]};
            *(d2*)&ib[t0 + j][p2] = c;
        }
        __syncthreads();
        if (tid < 64) {
            float* py = yg + ((size_t)(b * NO + o0 + tid)) * NT + tc;
            for (int tb = 0; tb < TT; tb += 16) {
                double iv[16];
                #pragma unroll
                for (int u = 0; u < 16; ++u) iv[u] = ib[tb + u][tid];
                float fv[16];
                #pragma unroll
                for (int u = 0; u < 16; ++u) {
                    v += (iv[u] - v) * alpha;
                    const bool s = (v >= 1.0);
                    fv[u] = s ? 1.0f : 0.0f;
                    if (s) v = 0.0;
                }
                #pragma unroll
                for (int q = 0; q < 4; ++q)
                    if (tb + q * 4 < tlim)
                        *(float4*)(py + tb + q * 4) =
                            make_float4(fv[q*4], fv[q*4+1], fv[q*4+2], fv[q*4+3]);
            }
        }
    }
}

extern "C" void kernel_launch(void* const* d_in, const int* in_sizes, int n_in,
                              void* d_out, int out_size, void* d_ws, size_t ws_size,
                              hipStream_t stream) {
    const float* x = (const float*)d_in[0];   // [64, 512, 500]
    const float* w = (const float*)d_in[1];   // [512, 512]
    float* y = (float*)d_out;                 // [64, 512, 500]
    (void)in_sizes; (void)n_in; (void)out_size;

    if (ws_size >= WS_NEED) {
        unsigned char* xt  = (unsigned char*)d_ws;
        unsigned char* wtb = (unsigned char*)d_ws + XT_BYTES;
        prep_xw<<<520, 256, 0, stream>>>(x, w, xt, wtb);
        snn_i8x8<<<512, 512, 0, stream>>>(xt, wtb, y);      // 4 waves/SIMD
    } else {
        snn_v2<<<512, 256, 0, stream>>>(x, w, y);           // ws-free fallback
    }
}

// Round 18
// 180.049 us; speedup vs baseline: 1.0925x; 1.0925x over previous
//
#include <hip/hip_runtime.h>

// SNN layer on MI355X. i[t,b,o] = sum_k x[b,k,t]*w[k,o]; per-(b,o) sequential
// LIF scan over t; spikes (0/1) fp32 [B,O,T].
//
// FINAL (r16 config, measured 180.46us total, absmax 0.0 — best of 17 rounds).
//
// Exact fixed-point i8-MFMA path: X=rint(x*2^28) -> 4 signed i8 limbs,
// W=rint(w*2^15) -> 4 limbs; 13 limb pairs (p+q>=2) accumulated exactly in
// i32 (mfma_i32_16x16x64_i8), combined in fp64; eps_i ~ 3e-4 vs ~2e-3
// budget. Integer accumulation exact -> instruction order irrelevant.
//
// Key structure (measured ledger):
// - prep_xw: x -> XT [b][limb][k/16][t][16] i8 fragments; w -> WT likewise.
// - snn_i8v5: register-direct fragments from XT/WT (no operand LDS),
//   32t x 32o wave tile, 4 waves/block, grid 512, fused in-LDS scan.
// - SLOT reorder (13 limb-pair slots x 4 independent (ta,oc) MFMAs): the
//   single biggest win — VGPR 128->68, FETCH 434->42MB, 225->148us.
// - XCD swizzle: 8 o-tiles of one batch share an XCD; batch XT (1MB) stays
//   L2-resident so redundant A-reads never hit HBM.
// Falsified: reg ping-pong (r9), LDS pipeline (r10), sched_barrier (r11),
// small-tile TLP (r12, 2x traffic), 8-wave blocks (r13/r14 spill; r17 clean
// but VGPR 116 kept cap at 4 waves/SIMD and added barrier cost, -9%).

#define NB 64
#define NI 512
#define NO 512
#define NT 500

typedef int v4i __attribute__((ext_vector_type(4)));
typedef double d2 __attribute__((ext_vector_type(2)));

#define XT_B_STRIDE 1048576   // bytes per batch in XT
#define P_STRIDE    262144    // bytes per limb plane
#define KB_STRIDE   8192      // bytes per k-block (512 rows * 16B)
#define XT_BYTES    67108864
#define WT_BYTES    1048576
#define WS_NEED     ((size_t)XT_BYTES + WT_BYTES)   // 68,157,440

// ============ prep: x transpose+limb-slice (blocks 0..511), w (512..519) ====
__global__ __launch_bounds__(256)
void prep_xw(const float* __restrict__ xg, const float* __restrict__ wg,
             unsigned char* __restrict__ xt, unsigned char* __restrict__ wtb) {
    __shared__ float xs[64][65];
    const int tid = threadIdx.x;
    const int sk  = tid >> 2;
    const int st  = (tid & 3) * 16;
    const int ct  = tid & 63;
    const int ckb = tid >> 6;

    if (blockIdx.x < 512) {
        const int b  = blockIdx.x >> 3;
        const int kc = (blockIdx.x & 7) * 64;
        for (int tc = 0; tc < 512; tc += 64) {
            __syncthreads();
            const float* px = xg + ((size_t)(b * NI + kc + sk)) * NT + tc + st;
            #pragma unroll
            for (int e = 0; e < 16; ++e)
                xs[sk][st + e] = (tc + st + e < NT) ? px[e] : 0.0f;
            __syncthreads();

            unsigned int u0[4] = {0,0,0,0}, u1[4] = {0,0,0,0};
            unsigned int u2[4] = {0,0,0,0}, u3[4] = {0,0,0,0};
            #pragma unroll
            for (int e = 0; e < 16; ++e) {
                const float xv = xs[ckb * 16 + e][ct];
                int X = __float2int_rn(xv * 268435456.0f);    // x * 2^28
                const int a0 = (X << 24) >> 24; X = (X - a0) >> 8;
                const int a1 = (X << 24) >> 24; X = (X - a1) >> 8;
                const int a2 = (X << 24) >> 24; const int a3 = (X - a2) >> 8;
                const int sh = (e & 3) * 8; const int d = e >> 2;
                u0[d] |= (unsigned)(a0 & 0xFF) << sh;
                u1[d] |= (unsigned)(a1 & 0xFF) << sh;
                u2[d] |= (unsigned)(a2 & 0xFF) << sh;
                u3[d] |= (unsigned)(a3 & 0xFF) << sh;
            }
            unsigned char* base = xt + (size_t)b * XT_B_STRIDE
                                  + (size_t)(kc / 16 + ckb) * KB_STRIDE
                                  + (size_t)(tc + ct) * 16;
            *(uint4*)(base)                = make_uint4(u0[0], u0[1], u0[2], u0[3]);
            *(uint4*)(base + P_STRIDE)     = make_uint4(u1[0], u1[1], u1[2], u1[3]);
            *(uint4*)(base + 2 * P_STRIDE) = make_uint4(u2[0], u2[1], u2[2], u2[3]);
            *(uint4*)(base + 3 * P_STRIDE) = make_uint4(u3[0], u3[1], u3[2], u3[3]);
        }
    } else {
        const int kc = (blockIdx.x - 512) * 64;
        for (int oc = 0; oc < 512; oc += 64) {
            __syncthreads();
            const float* pw = wg + (size_t)(kc + sk) * NO + oc + st;
            #pragma unroll
            for (int e = 0; e < 16; e += 4) {
                float4 f = *(const float4*)(pw + e);
                xs[sk][st + e + 0] = f.x; xs[sk][st + e + 1] = f.y;
                xs[sk][st + e + 2] = f.z; xs[sk][st + e + 3] = f.w;
            }
            __syncthreads();

            unsigned int u0[4] = {0,0,0,0}, u1[4] = {0,0,0,0};
            unsigned int u2[4] = {0,0,0,0}, u3[4] = {0,0,0,0};
            #pragma unroll
            for (int e = 0; e < 16; ++e) {
                const float wv = xs[ckb * 16 + e][ct];
                int X = __float2int_rn(wv * 32768.0f);        // w * 2^15
                const int a0 = (X << 24) >> 24; X = (X - a0) >> 8;
                const int a1 = (X << 24) >> 24; X = (X - a1) >> 8;
                const int a2 = (X << 24) >> 24; const int a3 = (X - a2) >> 8;
                const int sh = (e & 3) * 8; const int d = e >> 2;
                u0[d] |= (unsigned)(a0 & 0xFF) << sh;
                u1[d] |= (unsigned)(a1 & 0xFF) << sh;
                u2[d] |= (unsigned)(a2 & 0xFF) << sh;
                u3[d] |= (unsigned)(a3 & 0xFF) << sh;
            }
            unsigned char* base = wtb + (size_t)(kc / 16 + ckb) * KB_STRIDE
                                  + (size_t)(oc + ct) * 16;
            *(uint4*)(base)                = make_uint4(u0[0], u0[1], u0[2], u0[3]);
            *(uint4*)(base + P_STRIDE)     = make_uint4(u1[0], u1[1], u1[2], u1[3]);
            *(uint4*)(base + 2 * P_STRIDE) = make_uint4(u2[0], u2[1], u2[2], u2[3]);
            *(uint4*)(base + 3 * P_STRIDE) = make_uint4(u3[0], u3[1], u3[2], u3[3]);
        }
    }
}

// ====== main: register-direct i8-MFMA GEMM + fused scan (r16 optimum) ======
#define MFMA_I8(a, b, c) __builtin_amdgcn_mfma_i32_16x16x64_i8(a, b, c, 0, 0, 0)

// one limb-pair slot: 4 independent MFMAs (ta,oc); no same-acc adjacency
#define SLOT(ACC, AI, BI)                                              \
    _Pragma("unroll")                                                  \
    for (int ta = 0; ta < 2; ++ta) {                                   \
        _Pragma("unroll")                                              \
        for (int oc = 0; oc < 2; ++oc)                                 \
            ACC[ta][oc] = MFMA_I8(aF[ta][AI], bF[oc][BI], ACC[ta][oc]);\
    }

__global__ __launch_bounds__(256, 2)
void snn_i8v5(const unsigned char* __restrict__ xt,
              const unsigned char* __restrict__ wtb,
              float* __restrict__ yg) {
    __shared__ double ib[64][66];        // 33,792 B

    const int tid  = threadIdx.x;
    const int lane = tid & 63;
    const int wv   = tid >> 6;      // wave 0..3
    const int wt   = wv & 1;        // t-half (32 rows)
    const int wo   = wv >> 1;       // o-half (32 cols)
    const int lr   = lane & 15;
    const int lg   = lane >> 4;

    // XCD swizzle: 8 o-tiles of one batch share an XCD -> batch XT L2-hot.
    const int L  = blockIdx.x;
    const int b  = (L & 7) + ((L >> 6) << 3);
    const int o0 = ((L >> 3) & 7) * 64;

    const unsigned char* xb = xt + (size_t)b * XT_B_STRIDE;
    const unsigned char* wb = wtb + (size_t)o0 * 16;

    const double alpha = 0.001 / 50.0;
    double v = 0.0;                 // scan state (lanes<16 of each wave)

    for (int tc = 0; tc < 8; ++tc) {            // 8 chunks of 64 t (512 padded)
        v4i acc0[2][2], acc1[2][2], acc2[2][2], acc3[2][2], acc4[2][2];
        #pragma unroll
        for (int ta = 0; ta < 2; ++ta)
            #pragma unroll
            for (int oc = 0; oc < 2; ++oc) {
                acc0[ta][oc] = (v4i){0,0,0,0}; acc1[ta][oc] = (v4i){0,0,0,0};
                acc2[ta][oc] = (v4i){0,0,0,0}; acc3[ta][oc] = (v4i){0,0,0,0};
                acc4[ta][oc] = (v4i){0,0,0,0};
            }
        const int tbase = tc * 64 + wt * 32;

        for (int kw = 0; kw < 8; ++kw) {
            const size_t kb0 = (size_t)(kw * 4 + lg) * KB_STRIDE;
            v4i aF[2][4], bF[2][4];
            #pragma unroll
            for (int p = 0; p < 4; ++p) {
                const size_t pp = (size_t)p * P_STRIDE + kb0;
                #pragma unroll
                for (int ta = 0; ta < 2; ++ta)
                    aF[ta][p] = *(const v4i*)(xb + pp
                                 + (size_t)(tbase + ta * 16 + lr) * 16);
                #pragma unroll
                for (int oc = 0; oc < 2; ++oc)
                    bF[oc][p] = *(const v4i*)(wb + pp
                                 + (size_t)(wo * 32 + oc * 16 + lr) * 16);
            }
            // 13 limb-pair slots, interleaved across accumulators:
            SLOT(acc0, 0, 2)  SLOT(acc1, 0, 3)  SLOT(acc2, 1, 3)
            SLOT(acc3, 2, 3)  SLOT(acc4, 3, 3)
            SLOT(acc0, 1, 1)  SLOT(acc1, 1, 2)  SLOT(acc2, 2, 2)
            SLOT(acc3, 3, 2)
            SLOT(acc0, 2, 0)  SLOT(acc1, 2, 1)  SLOT(acc2, 3, 1)
            SLOT(acc1, 3, 0)
        }

        __syncthreads();   // previous chunk's scan reads complete
        // D: col = lane&15 (o), row = 4*(lane>>4)+reg (t) -- HW-verified.
        #pragma unroll
        for (int ta = 0; ta < 2; ++ta)
            #pragma unroll
            for (int oc = 0; oc < 2; ++oc) {
                const int o_loc = wo * 32 + oc * 16 + lr;
                #pragma unroll
                for (int r = 0; r < 4; ++r) {
                    const double iv =
                          (double)acc0[ta][oc][r] * 0x1p-27
                        + (double)acc1[ta][oc][r] * 0x1p-19
                        + (double)acc2[ta][oc][r] * 0x1p-11
                        + (double)acc3[ta][oc][r] * 0x1p-3
                        + (double)acc4[ta][oc][r] * 0x1p+5;
                    ib[wt * 32 + ta * 16 + lg * 4 + r][o_loc] = iv;
                }
            }
        __syncthreads();

        // ---- scan: each wave handles its 16 o-channels (lanes 0..15) ----
        if (lane < 16) {
            const int ol = wv * 16 + lane;               // local o 0..63
            float* py = yg + ((size_t)(b * NO) + o0 + ol) * NT + tc * 64;
            #pragma unroll
            for (int tb = 0; tb < 4; ++tb) {
                double iv[16];
                #pragma unroll
                for (int u = 0; u < 16; ++u) iv[u] = ib[tb * 16 + u][ol];
                float fv[16];
                #pragma unroll
                for (int u = 0; u < 16; ++u) {
                    v += (iv[u] - v) * alpha;
                    const bool s = (v >= 1.0);
                    fv[u] = s ? 1.0f : 0.0f;
                    if (s) v = 0.0;
                }
                const int tg = tc * 64 + tb * 16;
                #pragma unroll
                for (int q = 0; q < 4; ++q)
                    if (tg + q * 4 < NT)
                        *(float4*)(py + tb * 16 + q * 4) =
                            make_float4(fv[q*4], fv[q*4+1], fv[q*4+2], fv[q*4+3]);
            }
        }
    }
}

// ============ fallback: round-4 fused fp64 kernel (ws-free, proven) ============
#define OT 64
#define TT 64
#define KC 32
#define TP (TT + 2)
#define OP (OT + 2)

__global__ __launch_bounds__(256, 2)
void snn_v2(const float* __restrict__ xg, const float* __restrict__ wg,
            float* __restrict__ yg) {
    __shared__ double smem[KC * TP + KC * OP];
    double (*xs)[TP]  = (double(*)[TP])smem;
    double (*wsh)[OP] = (double(*)[OP])(smem + KC * TP);
    double (*ib)[OP]  = (double(*)[OP])smem;

    const int tid = threadIdx.x;
    const int p2  = (tid & 31) * 2;
    const int t0  = (tid >> 5) * 8;
    const int L   = blockIdx.x;
    const int b   = (L & 7) + ((L >> 6) << 3);
    const int o0  = ((L >> 3) & 7) * OT;
    const int sk  = tid >> 3;
    const int se  = (tid & 7) * 8;
    const double alpha = 0.001 / 50.0;
    double v = 0.0;

    for (int tc = 0; tc < NT; tc += TT) {
        const int tlim = (NT - tc < TT) ? (NT - tc) : TT;
        double a0[8], a1[8];
        #pragma unroll
        for (int j = 0; j < 8; ++j) { a0[j] = 0.0; a1[j] = 0.0; }

        for (int kc = 0; kc < NI; kc += KC) {
            __syncthreads();
            {
                const float* px = xg + ((size_t)(b * NI + kc + sk)) * NT + tc + se;
                double* dx = &xs[sk][se];
                if (tlim == TT) {
                    #pragma unroll
                    for (int e = 0; e < 2; ++e) {
                        float4 f = ((const float4*)px)[e];
                        d2 lo = {(double)f.x, (double)f.y};
                        d2 hi = {(double)f.z, (double)f.w};
                        *(d2*)(dx + e * 4) = lo; *(d2*)(dx + e * 4 + 2) = hi;
                    }
                } else {
                    #pragma unroll
                    for (int e = 0; e < 8; ++e) {
                        double val = 0.0;
                        if (se + e < tlim) val = (double)px[e];
                        dx[e] = val;
                    }
                }
            }
            {
                const float* pw = wg + (size_t)(kc + sk) * NO + o0 + se;
                double* dw = &wsh[sk][se];
                #pragma unroll
                for (int e = 0; e < 2; ++e) {
                    float4 f = ((const float4*)pw)[e];
                    d2 lo = {(double)f.x, (double)f.y};
                    d2 hi = {(double)f.z, (double)f.w};
                    *(d2*)(dw + e * 4) = lo; *(d2*)(dw + e * 4 + 2) = hi;
                }
            }
            __syncthreads();
            #pragma unroll 4
            for (int k = 0; k < KC; ++k) {
                const d2 w2 = *(const d2*)&wsh[k][p2];
                double x8[8];
                #pragma unroll
                for (int e = 0; e < 4; ++e)
                    *(d2*)&x8[e * 2] = *(const d2*)&xs[k][t0 + e * 2];
                #pragma unroll
                for (int j = 0; j < 8; ++j) {
                    a0[j] += x8[j] * w2[0];
                    a1[j] += x8[j] * w2[1];
                }
            }
        }
        __syncthreads();
        #pragma unroll
        for (int j = 0; j < 8; ++j) {
            d2 c = {a0[j], a1[j]};
            *(d2*)&ib[t0 + j][p2] = c;
        }
        __syncthreads();
        if (tid < 64) {
            float* py = yg + ((size_t)(b * NO + o0 + tid)) * NT + tc;
            for (int tb = 0; tb < TT; tb += 16) {
                double iv[16];
                #pragma unroll
                for (int u = 0; u < 16; ++u) iv[u] = ib[tb + u][tid];
                float fv[16];
                #pragma unroll
                for (int u = 0; u < 16; ++u) {
                    v += (iv[u] - v) * alpha;
                    const bool s = (v >= 1.0);
                    fv[u] = s ? 1.0f : 0.0f;
                    if (s) v = 0.0;
                }
                #pragma unroll
                for (int q = 0; q < 4; ++q)
                    if (tb + q * 4 < tlim)
                        *(float4*)(py + tb + q * 4) =
                            make_float4(fv[q*4], fv[q*4+1], fv[q*4+2], fv[q*4+3]);
            }
        }
    }
}

extern "C" void kernel_launch(void* const* d_in, const int* in_sizes, int n_in,
                              void* d_out, int out_size, void* d_ws, size_t ws_size,
                              hipStream_t stream) {
    const float* x = (const float*)d_in[0];   // [64, 512, 500]
    const float* w = (const float*)d_in[1];   // [512, 512]
    float* y = (float*)d_out;                 // [64, 512, 500]
    (void)in_sizes; (void)n_in; (void)out_size;

    if (ws_size >= WS_NEED) {
        unsigned char* xt  = (unsigned char*)d_ws;
        unsigned char* wtb = (unsigned char*)d_ws + XT_BYTES;
        prep_xw<<<520, 256, 0, stream>>>(x, w, xt, wtb);
        snn_i8v5<<<512, 256, 0, stream>>>(xt, wtb, y);      // r16-proven path
    } else {
        snn_v2<<<512, 256, 0, stream>>>(x, w, y);           // ws-free fallback
    }
}

// Round 19
// 149.413 us; speedup vs baseline: 1.3165x; 1.2050x over previous
//
#include <hip/hip_runtime.h>

// SNN layer on MI355X. i[t,b,o] = sum_k x[b,k,t]*w[k,o]; per-(b,o) sequential
// LIF scan over t; spikes (0/1) fp32 [B,O,T].
//
// r16 optimum (reproduced 2x: 180.46 / 180.05 us, absmax 0.0) + T5 setprio
// around the MFMA burst. K-loop has NO barriers -> waves on a CU free-run at
// independent phases (the m191 condition where setprio pays, not the m190
// lockstep condition where it is null). Pure scheduler hint, zero
// correctness risk; integer accumulation exact.
//
// Exact fixed-point i8-MFMA path: X=rint(x*2^28) -> 4 signed i8 limbs,
// W=rint(w*2^15) -> 4 limbs; 13 limb pairs (p+q>=2) accumulated exactly in
// i32 (mfma_i32_16x16x64_i8), combined in fp64; eps_i ~ 3e-4 vs ~2e-3.
//
// Measured ledger: SLOT reorder = the big win (VGPR 128->68, FETCH 434->42MB,
// 225->148us). Falsified: reg ping-pong (r9), LDS pipeline (r10),
// sched_barrier prefetch (r11), small-tile TLP (r12), 8-wave blocks
// (r13/r14 spill; r17 clean but -9%), t-split 2-kernel (r15).

#define NB 64
#define NI 512
#define NO 512
#define NT 500

typedef int v4i __attribute__((ext_vector_type(4)));
typedef double d2 __attribute__((ext_vector_type(2)));

#define XT_B_STRIDE 1048576   // bytes per batch in XT
#define P_STRIDE    262144    // bytes per limb plane
#define KB_STRIDE   8192      // bytes per k-block (512 rows * 16B)
#define XT_BYTES    67108864
#define WT_BYTES    1048576
#define WS_NEED     ((size_t)XT_BYTES + WT_BYTES)   // 68,157,440

// ============ prep: x transpose+limb-slice (blocks 0..511), w (512..519) ====
__global__ __launch_bounds__(256)
void prep_xw(const float* __restrict__ xg, const float* __restrict__ wg,
             unsigned char* __restrict__ xt, unsigned char* __restrict__ wtb) {
    __shared__ float xs[64][65];
    const int tid = threadIdx.x;
    const int sk  = tid >> 2;
    const int st  = (tid & 3) * 16;
    const int ct  = tid & 63;
    const int ckb = tid >> 6;

    if (blockIdx.x < 512) {
        const int b  = blockIdx.x >> 3;
        const int kc = (blockIdx.x & 7) * 64;
        for (int tc = 0; tc < 512; tc += 64) {
            __syncthreads();
            const float* px = xg + ((size_t)(b * NI + kc + sk)) * NT + tc + st;
            #pragma unroll
            for (int e = 0; e < 16; ++e)
                xs[sk][st + e] = (tc + st + e < NT) ? px[e] : 0.0f;
            __syncthreads();

            unsigned int u0[4] = {0,0,0,0}, u1[4] = {0,0,0,0};
            unsigned int u2[4] = {0,0,0,0}, u3[4] = {0,0,0,0};
            #pragma unroll
            for (int e = 0; e < 16; ++e) {
                const float xv = xs[ckb * 16 + e][ct];
                int X = __float2int_rn(xv * 268435456.0f);    // x * 2^28
                const int a0 = (X << 24) >> 24; X = (X - a0) >> 8;
                const int a1 = (X << 24) >> 24; X = (X - a1) >> 8;
                const int a2 = (X << 24) >> 24; const int a3 = (X - a2) >> 8;
                const int sh = (e & 3) * 8; const int d = e >> 2;
                u0[d] |= (unsigned)(a0 & 0xFF) << sh;
                u1[d] |= (unsigned)(a1 & 0xFF) << sh;
                u2[d] |= (unsigned)(a2 & 0xFF) << sh;
                u3[d] |= (unsigned)(a3 & 0xFF) << sh;
            }
            unsigned char* base = xt + (size_t)b * XT_B_STRIDE
                                  + (size_t)(kc / 16 + ckb) * KB_STRIDE
                                  + (size_t)(tc + ct) * 16;
            *(uint4*)(base)                = make_uint4(u0[0], u0[1], u0[2], u0[3]);
            *(uint4*)(base + P_STRIDE)     = make_uint4(u1[0], u1[1], u1[2], u1[3]);
            *(uint4*)(base + 2 * P_STRIDE) = make_uint4(u2[0], u2[1], u2[2], u2[3]);
            *(uint4*)(base + 3 * P_STRIDE) = make_uint4(u3[0], u3[1], u3[2], u3[3]);
        }
    } else {
        const int kc = (blockIdx.x - 512) * 64;
        for (int oc = 0; oc < 512; oc += 64) {
            __syncthreads();
            const float* pw = wg + (size_t)(kc + sk) * NO + oc + st;
            #pragma unroll
            for (int e = 0; e < 16; e += 4) {
                float4 f = *(const float4*)(pw + e);
                xs[sk][st + e + 0] = f.x; xs[sk][st + e + 1] = f.y;
                xs[sk][st + e + 2] = f.z; xs[sk][st + e + 3] = f.w;
            }
            __syncthreads();

            unsigned int u0[4] = {0,0,0,0}, u1[4] = {0,0,0,0};
            unsigned int u2[4] = {0,0,0,0}, u3[4] = {0,0,0,0};
            #pragma unroll
            for (int e = 0; e < 16; ++e) {
                const float wv = xs[ckb * 16 + e][ct];
                int X = __float2int_rn(wv * 32768.0f);        // w * 2^15
                const int a0 = (X << 24) >> 24; X = (X - a0) >> 8;
                const int a1 = (X << 24) >> 24; X = (X - a1) >> 8;
                const int a2 = (X << 24) >> 24; const int a3 = (X - a2) >> 8;
                const int sh = (e & 3) * 8; const int d = e >> 2;
                u0[d] |= (unsigned)(a0 & 0xFF) << sh;
                u1[d] |= (unsigned)(a1 & 0xFF) << sh;
                u2[d] |= (unsigned)(a2 & 0xFF) << sh;
                u3[d] |= (unsigned)(a3 & 0xFF) << sh;
            }
            unsigned char* base = wtb + (size_t)(kc / 16 + ckb) * KB_STRIDE
                                  + (size_t)(oc + ct) * 16;
            *(uint4*)(base)                = make_uint4(u0[0], u0[1], u0[2], u0[3]);
            *(uint4*)(base + P_STRIDE)     = make_uint4(u1[0], u1[1], u1[2], u1[3]);
            *(uint4*)(base + 2 * P_STRIDE) = make_uint4(u2[0], u2[1], u2[2], u2[3]);
            *(uint4*)(base + 3 * P_STRIDE) = make_uint4(u3[0], u3[1], u3[2], u3[3]);
        }
    }
}

// ====== main: register-direct i8-MFMA GEMM + fused scan (r16 + setprio) ======
#define MFMA_I8(a, b, c) __builtin_amdgcn_mfma_i32_16x16x64_i8(a, b, c, 0, 0, 0)

// one limb-pair slot: 4 independent MFMAs (ta,oc); no same-acc adjacency
#define SLOT(ACC, AI, BI)                                              \
    _Pragma("unroll")                                                  \
    for (int ta = 0; ta < 2; ++ta) {                                   \
        _Pragma("unroll")                                              \
        for (int oc = 0; oc < 2; ++oc)                                 \
            ACC[ta][oc] = MFMA_I8(aF[ta][AI], bF[oc][BI], ACC[ta][oc]);\
    }

__global__ __launch_bounds__(256, 2)
void snn_i8v5(const unsigned char* __restrict__ xt,
              const unsigned char* __restrict__ wtb,
              float* __restrict__ yg) {
    __shared__ double ib[64][66];        // 33,792 B

    const int tid  = threadIdx.x;
    const int lane = tid & 63;
    const int wv   = tid >> 6;      // wave 0..3
    const int wt   = wv & 1;        // t-half (32 rows)
    const int wo   = wv >> 1;       // o-half (32 cols)
    const int lr   = lane & 15;
    const int lg   = lane >> 4;

    // XCD swizzle: 8 o-tiles of one batch share an XCD -> batch XT L2-hot.
    const int L  = blockIdx.x;
    const int b  = (L & 7) + ((L >> 6) << 3);
    const int o0 = ((L >> 3) & 7) * 64;

    const unsigned char* xb = xt + (size_t)b * XT_B_STRIDE;
    const unsigned char* wb = wtb + (size_t)o0 * 16;

    const double alpha = 0.001 / 50.0;
    double v = 0.0;                 // scan state (lanes<16 of each wave)

    for (int tc = 0; tc < 8; ++tc) {            // 8 chunks of 64 t (512 padded)
        v4i acc0[2][2], acc1[2][2], acc2[2][2], acc3[2][2], acc4[2][2];
        #pragma unroll
        for (int ta = 0; ta < 2; ++ta)
            #pragma unroll
            for (int oc = 0; oc < 2; ++oc) {
                acc0[ta][oc] = (v4i){0,0,0,0}; acc1[ta][oc] = (v4i){0,0,0,0};
                acc2[ta][oc] = (v4i){0,0,0,0}; acc3[ta][oc] = (v4i){0,0,0,0};
                acc4[ta][oc] = (v4i){0,0,0,0};
            }
        const int tbase = tc * 64 + wt * 32;

        for (int kw = 0; kw < 8; ++kw) {
            const size_t kb0 = (size_t)(kw * 4 + lg) * KB_STRIDE;
            v4i aF[2][4], bF[2][4];
            #pragma unroll
            for (int p = 0; p < 4; ++p) {
                const size_t pp = (size_t)p * P_STRIDE + kb0;
                #pragma unroll
                for (int ta = 0; ta < 2; ++ta)
                    aF[ta][p] = *(const v4i*)(xb + pp
                                 + (size_t)(tbase + ta * 16 + lr) * 16);
                #pragma unroll
                for (int oc = 0; oc < 2; ++oc)
                    bF[oc][p] = *(const v4i*)(wb + pp
                                 + (size_t)(wo * 32 + oc * 16 + lr) * 16);
            }
            // T5: waves are NOT barrier-synced here -> MFMA-ready waves get
            // priority over load-issuing waves on the CU scheduler.
            __builtin_amdgcn_s_setprio(1);
            // 13 limb-pair slots, interleaved across accumulators:
            SLOT(acc0, 0, 2)  SLOT(acc1, 0, 3)  SLOT(acc2, 1, 3)
            SLOT(acc3, 2, 3)  SLOT(acc4, 3, 3)
            SLOT(acc0, 1, 1)  SLOT(acc1, 1, 2)  SLOT(acc2, 2, 2)
            SLOT(acc3, 3, 2)
            SLOT(acc0, 2, 0)  SLOT(acc1, 2, 1)  SLOT(acc2, 3, 1)
            SLOT(acc1, 3, 0)
            __builtin_amdgcn_s_setprio(0);
        }

        __syncthreads();   // previous chunk's scan reads complete
        // D: col = lane&15 (o), row = 4*(lane>>4)+reg (t) -- HW-verified.
        #pragma unroll
        for (int ta = 0; ta < 2; ++ta)
            #pragma unroll
            for (int oc = 0; oc < 2; ++oc) {
                const int o_loc = wo * 32 + oc * 16 + lr;
                #pragma unroll
                for (int r = 0; r < 4; ++r) {
                    const double iv =
                          (double)acc0[ta][oc][r] * 0x1p-27
                        + (double)acc1[ta][oc][r] * 0x1p-19
                        + (double)acc2[ta][oc][r] * 0x1p-11
                        + (double)acc3[ta][oc][r] * 0x1p-3
                        + (double)acc4[ta][oc][r] * 0x1p+5;
                    ib[wt * 32 + ta * 16 + lg * 4 + r][o_loc] = iv;
                }
            }
        __syncthreads();

        // ---- scan: each wave handles its 16 o-channels (lanes 0..15) ----
        if (lane < 16) {
            const int ol = wv * 16 + lane;               // local o 0..63
            float* py = yg + ((size_t)(b * NO) + o0 + ol) * NT + tc * 64;
            #pragma unroll
            for (int tb = 0; tb < 4; ++tb) {
                double iv[16];
                #pragma unroll
                for (int u = 0; u < 16; ++u) iv[u] = ib[tb * 16 + u][ol];
                float fv[16];
                #pragma unroll
                for (int u = 0; u < 16; ++u) {
                    v += (iv[u] - v) * alpha;
                    const bool s = (v >= 1.0);
                    fv[u] = s ? 1.0f : 0.0f;
                    if (s) v = 0.0;
                }
                const int tg = tc * 64 + tb * 16;
                #pragma unroll
                for (int q = 0; q < 4; ++q)
                    if (tg + q * 4 < NT)
                        *(float4*)(py + tb * 16 + q * 4) =
                            make_float4(fv[q*4], fv[q*4+1], fv[q*4+2], fv[q*4+3]);
            }
        }
    }
}

// ============ fallback: round-4 fused fp64 kernel (ws-free, proven) ============
#define OT 64
#define TT 64
#define KC 32
#define TP (TT + 2)
#define OP (OT + 2)

__global__ __launch_bounds__(256, 2)
void snn_v2(const float* __restrict__ xg, const float* __restrict__ wg,
            float* __restrict__ yg) {
    __shared__ double smem[KC * TP + KC * OP];
    double (*xs)[TP]  = (double(*)[TP])smem;
    double (*wsh)[OP] = (double(*)[OP])(smem + KC * TP);
    double (*ib)[OP]  = (double(*)[OP])smem;

    const int tid = threadIdx.x;
    const int p2  = (tid & 31) * 2;
    const int t0  = (tid >> 5) * 8;
    const int L   = blockIdx.x;
    const int b   = (L & 7) + ((L >> 6) << 3);
    const int o0  = ((L >> 3) & 7) * OT;
    const int sk  = tid >> 3;
    const int se  = (tid & 7) * 8;
    const double alpha = 0.001 / 50.0;
    double v = 0.0;

    for (int tc = 0; tc < NT; tc += TT) {
        const int tlim = (NT - tc < TT) ? (NT - tc) : TT;
        double a0[8], a1[8];
        #pragma unroll
        for (int j = 0; j < 8; ++j) { a0[j] = 0.0; a1[j] = 0.0; }

        for (int kc = 0; kc < NI; kc += KC) {
            __syncthreads();
            {
                const float* px = xg + ((size_t)(b * NI + kc + sk)) * NT + tc + se;
                double* dx = &xs[sk][se];
                if (tlim == TT) {
                    #pragma unroll
                    for (int e = 0; e < 2; ++e) {
                        float4 f = ((const float4*)px)[e];
                        d2 lo = {(double)f.x, (double)f.y};
                        d2 hi = {(double)f.z, (double)f.w};
                        *(d2*)(dx + e * 4) = lo; *(d2*)(dx + e * 4 + 2) = hi;
                    }
                } else {
                    #pragma unroll
                    for (int e = 0; e < 8; ++e) {
                        double val = 0.0;
                        if (se + e < tlim) val = (double)px[e];
                        dx[e] = val;
                    }
                }
            }
            {
                const float* pw = wg + (size_t)(kc + sk) * NO + o0 + se;
                double* dw = &wsh[sk][se];
                #pragma unroll
                for (int e = 0; e < 2; ++e) {
                    float4 f = ((const float4*)pw)[e];
                    d2 lo = {(double)f.x, (double)f.y};
                    d2 hi = {(double)f.z, (double)f.w};
                    *(d2*)(dw + e * 4) = lo; *(d2*)(dw + e * 4 + 2) = hi;
                }
            }
            __syncthreads();
            #pragma unroll 4
            for (int k = 0; k < KC; ++k) {
                const d2 w2 = *(const d2*)&wsh[k][p2];
                double x8[8];
                #pragma unroll
                for (int e = 0; e < 4; ++e)
                    *(d2*)&x8[e * 2] = *(const d2*)&xs[k][t0 + e * 2];
                #pragma unroll
                for (int j = 0; j < 8; ++j) {
                    a0[j] += x8[j] * w2[0];
                    a1[j] += x8[j] * w2[1];
                }
            }
        }
        __syncthreads();
        #pragma unroll
        for (int j = 0; j < 8; ++j) {
            d2 c = {a0[j], a1[j]};
            *(d2*)&ib[t0 + j][p2] = c;
        }
        __syncthreads();
        if (tid < 64) {
            float* py = yg + ((size_t)(b * NO + o0 + tid)) * NT + tc;
            for (int tb = 0; tb < TT; tb += 16) {
                double iv[16];
                #pragma unroll
                for (int u = 0; u < 16; ++u) iv[u] = ib[tb + u][tid];
                float fv[16];
                #pragma unroll
                for (int u = 0; u < 16; ++u) {
                    v += (iv[u] - v) * alpha;
                    const bool s = (v >= 1.0);
                    fv[u] = s ? 1.0f : 0.0f;
                    if (s) v = 0.0;
                }
                #pragma unroll
                for (int q = 0; q < 4; ++q)
                    if (tb + q * 4 < tlim)
                        *(float4*)(py + tb + q * 4) =
                            make_float4(fv[q*4], fv[q*4+1], fv[q*4+2], fv[q*4+3]);
            }
        }
    }
}

extern "C" void kernel_launch(void* const* d_in, const int* in_sizes, int n_in,
                              void* d_out, int out_size, void* d_ws, size_t ws_size,
                              hipStream_t stream) {
    const float* x = (const float*)d_in[0];   // [64, 512, 500]
    const float* w = (const float*)d_in[1];   // [512, 512]
    float* y = (float*)d_out;                 // [64, 512, 500]
    (void)in_sizes; (void)n_in; (void)out_size;

    if (ws_size >= WS_NEED) {
        unsigned char* xt  = (unsigned char*)d_ws;
        unsigned char* wtb = (unsigned char*)d_ws + XT_BYTES;
        prep_xw<<<520, 256, 0, stream>>>(x, w, xt, wtb);
        snn_i8v5<<<512, 256, 0, stream>>>(xt, wtb, y);      // r16 + setprio
    } else {
        snn_v2<<<512, 256, 0, stream>>>(x, w, y);           // ws-free fallback
    }
}